// Round 12
// baseline (3918.913 us; speedup 1.0000x reference)
//
#include <hip/hip_runtime.h>
#include <hip/hip_bf16.h>

// LSTM decoder B=256, T=512, H=1024 — persistent fp16 MFMA, v10.
// R11 lesson: finer-grained sync loses; v8's tid0-poll counter is optimal.
// v10 attacks the GLOBAL lockstep tail instead: 2 WGs/CU from INDEPENDENT
// m-groups (independent barriers -> phases drift) so one WG's K-loop overlaps
// the other's serial tail (poll/drain/reduction).
//   WG: 256 thr, N_wg=64 (4g x 16j), M_wg=32; waves = 2m x 2k.
//   W slice 128 KB: gates 0,1 in 64 KB LDS; gates 2,3 in 128 VGPRs (per k-half).
//   LDS 64+16 = 80 KB -> exactly 2 WGs/CU; grid 512 (all co-resident).
//   2-way K-split -> single-round reduction (one fewer sync than v8).
//   A loads agent-scope u64, 8-deep ring; h stores u32 sc0sc1 (256B/wave lines);
//   barrier: per-gm counter, target 64(t+1), tid0 add+poll (v8-proven).

#define BB 256
#define TT 512
#define HH 1024

typedef __attribute__((ext_vector_type(8))) short short8;
typedef __attribute__((ext_vector_type(8))) _Float16 half8;
typedef __attribute__((ext_vector_type(4))) float float4v;

#define HP_U64 ((size_t)65536)   // u64 per h buffer: 256 U-units x 256 rows

__device__ __forceinline__ float sigf(float x) { return 1.0f / (1.0f + __expf(-x)); }
__device__ __forceinline__ float tanhff(float x) {
    return 1.0f - 2.0f / (__expf(2.0f * x) + 1.0f);
}

// ---- pack W_hh (4096x1024 f32) -> fp16 B-fragment order (R7-proven) ----
// Wp[jt(64)][kc(32)][g(4)][lane(64)][8] ; per-jt block = 128 KB
__global__ __launch_bounds__(256) void pack_w(const float* __restrict__ W_hh,
                                              unsigned short* __restrict__ Wp) {
    int fid = blockIdx.x * 256 + threadIdx.x;   // 0..524287
    int lane = fid & 63;
    int g = (fid >> 6) & 3;
    int kc = (fid >> 8) & 31;
    int jt = fid >> 13;
    int row = g * HH + jt * 16 + (lane & 15);
    int k = kc * 32 + (lane >> 4) * 8;
    const float* src = W_hh + (size_t)row * HH + k;
    union { _Float16 h[8]; short8 s; } u;
#pragma unroll
    for (int e = 0; e < 8; ++e) u.h[e] = (_Float16)src[e];
    *(short8*)(Wp + (size_t)fid * 8) = u.s;
}

// ---- h0 -> fp16 fragment layout in buffer 0; zero barrier counters ----
// unit U=(k>>5)*8+((k>>2)&7); u64 idx = U*256 + M
__global__ __launch_bounds__(256) void prep_state(const float* __restrict__ h0,
                                                  unsigned long long* __restrict__ hb0,
                                                  unsigned int* __restrict__ cnt) {
    int gid = blockIdx.x * 256 + threadIdx.x;   // 0..65535
    int r = gid & 255;
    int U = gid >> 8;
    int kb = (U >> 3) * 32 + ((U >> 1) & 3) * 8 + (U & 1) * 4;
    float4 v = *(const float4*)(h0 + (size_t)r * HH + kb);
    union { _Float16 h[4]; unsigned long long u; } x;
    x.h[0] = (_Float16)v.x; x.h[1] = (_Float16)v.y;
    x.h[2] = (_Float16)v.z; x.h[3] = (_Float16)v.w;
    hb0[(size_t)U * 256 + r] = x.u;
    if (blockIdx.x == 0) cnt[threadIdx.x] = 0;   // 8 groups x 32-u32 lines
}

// ---- persistent LSTM kernel: all 512 steps + final FC ----
__global__ __launch_bounds__(256, 2) void lstm_persist(
    const float* __restrict__ y_hist,
    const float* __restrict__ W_ih,           // (4096) flat
    const float* __restrict__ b_ih,
    const float* __restrict__ b_hh,
    const float* __restrict__ c0,             // (B,H) f32
    const float* __restrict__ W_fc,           // (H)
    const float* __restrict__ b_fc,           // (1)
    const unsigned short* __restrict__ Wp,    // packed fp16 W fragments
    unsigned long long* hbase,                // 2 buffers x HP_U64 u64
    unsigned int* cnt,                        // cnt[gm(8)] on 128B lines
    float* __restrict__ out)
{
    __shared__ __align__(16) unsigned short Wlds[32768];   // 64 KB: gates 0,1
    __shared__ __align__(16) float scr[4096];              // 16 KB: 4 regions x 1024
    // 80 KiB -> exactly 2 WGs/CU; grid=512 => all co-resident.
    // bid<256 -> gm 0..3, bid>=256 -> gm 4..7: each CU hosts two INDEPENDENT
    // m-group chains whose barriers drift -> tails overlap compute.

    const int tid = threadIdx.x;
    const int lane = tid & 63;
    const int wv = tid >> 6;                   // 0..3
    const int m2 = wv & 1;                     // m half (16 rows)
    const int k2 = wv >> 1;                    // K half (512 k)
    const int bid = blockIdx.x;
    const int gm = bid >> 6;                   // m-group 0..7 (32 rows)
    const int jt = bid & 63;                   // 16-j tile

    const unsigned short* WpJ = Wp + (size_t)jt * 65536;

    // --- LDS: gates 0,1 fragments (all kc) ---
    for (int f = tid; f < 4096; f += 256) {
        int kc = f >> 7, g = (f >> 6) & 1, l = f & 63;
        *(short8*)&Wlds[(size_t)((kc * 2 + g) * 64 + l) * 8] =
            *(const short8*)(WpJ + (size_t)((kc * 4 + g) * 64 + l) * 8);
    }
    // --- registers: gates 2,3 fragments for this wave's K-half (128 VGPR) ---
    half8 Breg[16][2];   // [c][g-2]
#pragma unroll
    for (int c = 0; c < 16; ++c) {
        int kc = k2 * 16 + c;
#pragma unroll
        for (int g2 = 0; g2 < 2; ++g2)
            Breg[c][g2] = *(const half8*)
                (WpJ + (size_t)(((kc * 4 + 2 + g2) * 64 + lane)) * 8);
    }

    // --- A addressing ---
    const int blk = gm * 2 + m2;               // 16-row block 0..15
    const int q = lane >> 4;
    const size_t abase = (size_t)blk * 16 + (lane & 15);
    const size_t qoff = (size_t)q * 512;

    // --- epilogue constants (all 256 threads: cell = 1 row x 2 j) ---
    const int em = tid & 31;                   // tile-local row
    const int jp = tid >> 5;                   // j-pair 0..7
    const int jq = jp >> 1;
    const int M = gm * 32 + em;
    float wi_[4][2], bs_[4][2], c_[2];
#pragma unroll
    for (int g = 0; g < 4; ++g)
#pragma unroll
        for (int jj = 0; jj < 2; ++jj) {
            int j = jt * 16 + jp * 2 + jj;
            wi_[g][jj] = W_ih[g * HH + j];
            bs_[g][jj] = b_ih[g * HH + j] + b_hh[g * HH + j];
        }
#pragma unroll
    for (int jj = 0; jj < 2; ++jj)
        c_[jj] = c0[(size_t)M * HH + jt * 16 + jp * 2 + jj];
    // u32 store idx: U = jt*4 + jq -> ((jt*4+jq)*256 + M)*2 + (jp&1)
    const size_t sidx32 = ((size_t)(jt * 4 + jq) * 256 + M) * 2 + (jp & 1);

    __syncthreads();   // Wlds visible

    unsigned int* mycnt = cnt + gm * 32;
    const int ml = q * 4;                      // local row base within 16-row tile

    for (int t = 0; t < TT; ++t) {
        const unsigned long long* hR = hbase + (size_t)(t & 1) * HP_U64;
        unsigned long long* hW = hbase + (size_t)((t + 1) & 1) * HP_U64;

        // prefetch y_hist x (hides under K-loop)
        float x = y_hist[(size_t)M * TT + t];

        float4v acc[4] = {{0.f,0.f,0.f,0.f},{0.f,0.f,0.f,0.f},
                          {0.f,0.f,0.f,0.f},{0.f,0.f,0.f,0.f}};

        // --- sync-free K-loop: 16 chunks of K=32, 8-deep A prefetch ring ---
        unsigned long long ring[8][2];
#pragma unroll
        for (int p = 0; p < 8; ++p) {
            size_t ua = (size_t)(k2 * 16 + p) * 2048 + qoff + abase;
            ring[p][0] = __hip_atomic_load((unsigned long long*)&hR[ua],
                                           __ATOMIC_RELAXED, __HIP_MEMORY_SCOPE_AGENT);
            ring[p][1] = __hip_atomic_load((unsigned long long*)&hR[ua + 256],
                                           __ATOMIC_RELAXED, __HIP_MEMORY_SCOPE_AGENT);
        }
#pragma unroll
        for (int ch = 0; ch < 16; ++ch) {
            union { unsigned long long u[2]; half8 h; } af;
            af.u[0] = ring[ch & 7][0];
            af.u[1] = ring[ch & 7][1];
            if (ch < 8) {
                size_t ua = (size_t)(k2 * 16 + ch + 8) * 2048 + qoff + abase;
                ring[ch & 7][0] = __hip_atomic_load((unsigned long long*)&hR[ua],
                                                    __ATOMIC_RELAXED, __HIP_MEMORY_SCOPE_AGENT);
                ring[ch & 7][1] = __hip_atomic_load((unsigned long long*)&hR[ua + 256],
                                                    __ATOMIC_RELAXED, __HIP_MEMORY_SCOPE_AGENT);
            }
            const int kc = k2 * 16 + ch;
#pragma unroll
            for (int g = 0; g < 2; ++g) {
                half8 bh = *(const half8*)&Wlds[(size_t)((kc * 2 + g) * 64 + lane) * 8];
                acc[g] = __builtin_amdgcn_mfma_f32_16x16x32_f16(af.h, bh, acc[g], 0, 0, 0);
            }
#pragma unroll
            for (int g2 = 0; g2 < 2; ++g2)
                acc[2 + g2] = __builtin_amdgcn_mfma_f32_16x16x32_f16(af.h, Breg[ch][g2],
                                                                     acc[2 + g2], 0, 0, 0);
        }

        // --- single-round 2-way k-reduction in 16 KB scratch ---
        // region layout: [n(64)][16] with slot swizzle ml^((n&3)<<2) (v8 math)
        if (k2 == 1) {
#pragma unroll
            for (int a = 0; a < 4; ++a) {
                int n = a * 16 + (lane & 15);
                *(float4v*)&scr[m2 * 1024 + n * 16 + (ml ^ ((n & 3) << 2))] = acc[a];
            }
        }
        __syncthreads();
        if (k2 == 0) {
#pragma unroll
            for (int a = 0; a < 4; ++a) {
                int n = a * 16 + (lane & 15);
                int sw = n * 16 + (ml ^ ((n & 3) << 2));
                acc[a] += *(const float4v*)&scr[m2 * 1024 + sw];
                *(float4v*)&scr[(2 + m2) * 1024 + sw] = acc[a];   // final G
            }
        }
        __syncthreads();

        // --- epilogue (all 256 threads): 1 row x 2 j; one u32 sc0sc1 store ---
        {
            int rbase = (2 + (em >> 4)) * 1024;
            union { _Float16 h[2]; unsigned int u; } hv;
#pragma unroll
            for (int jj = 0; jj < 2; ++jj) {
                int jl = jp * 2 + jj;                      // 0..15
                int msw = (em & 15) ^ ((jl & 3) << 2);
                float gi = scr[rbase + (0 * 16 + jl) * 16 + msw] + x * wi_[0][jj] + bs_[0][jj];
                float gf = scr[rbase + (1 * 16 + jl) * 16 + msw] + x * wi_[1][jj] + bs_[1][jj];
                float gg = scr[rbase + (2 * 16 + jl) * 16 + msw] + x * wi_[2][jj] + bs_[2][jj];
                float go = scr[rbase + (3 * 16 + jl) * 16 + msw] + x * wi_[3][jj] + bs_[3][jj];
                float cn = sigf(gf) * c_[jj] + sigf(gi) * tanhff(gg);
                float hn = sigf(go) * tanhff(cn);
                c_[jj] = cn;
                hv.h[jj] = (_Float16)hn;
            }
            asm volatile("global_store_dword %0, %1, off sc0 sc1"
                         : : "v"((void*)((unsigned int*)hW + sidx32)), "v"(hv.u) : "memory");
        }

        // --- drain stores, then per-gm barrier (64 WGs, tid0 add+poll) ---
        asm volatile("s_waitcnt vmcnt(0)" ::: "memory");
        __syncthreads();
        if (tid == 0) {
            __hip_atomic_fetch_add(mycnt, 1u, __ATOMIC_RELAXED, __HIP_MEMORY_SCOPE_AGENT);
            unsigned target = 64u * (unsigned)(t + 1);
            while (__hip_atomic_load(mycnt, __ATOMIC_RELAXED, __HIP_MEMORY_SCOPE_AGENT) <
                   target)
                __builtin_amdgcn_s_sleep(1);
        }
        __syncthreads();
    }

    // --- final FC (h final in buffer 0): jt==0 WGs, k2==0 waves ---
    if (jt == 0 && k2 == 0) {
        const unsigned long long* hF = hbase;   // buffer 0 (T even)
#pragma unroll 1
        for (int rr = 0; rr < 16; ++rr) {
            int row = gm * 32 + m2 * 16 + rr;
            float s = 0.f;
#pragma unroll 1
            for (int uu = 0; uu < 4; ++uu) {
                int U = uu * 64 + lane;
                unsigned long long u = __hip_atomic_load(
                    (unsigned long long*)&hF[(size_t)U * 256 + row],
                    __ATOMIC_RELAXED, __HIP_MEMORY_SCOPE_AGENT);
                int kb = (U >> 3) * 32 + ((U >> 1) & 3) * 8 + (U & 1) * 4;
                union { _Float16 h[4]; unsigned long long x; } v;
                v.x = u;
                float4 wf = *(const float4*)(W_fc + kb);
                s += (float)v.h[0] * wf.x + (float)v.h[1] * wf.y +
                     (float)v.h[2] * wf.z + (float)v.h[3] * wf.w;
            }
#pragma unroll
            for (int off = 32; off > 0; off >>= 1) s += __shfl_xor(s, off);
            if (lane == 0) out[row] = s + b_fc[0];
        }
    }
}

extern "C" void kernel_launch(void* const* d_in, const int* in_sizes, int n_in,
                              void* d_out, int out_size, void* d_ws, size_t ws_size,
                              hipStream_t stream) {
    const float* y_hist = (const float*)d_in[0];
    const float* W_ih   = (const float*)d_in[1];
    const float* W_hh   = (const float*)d_in[2];
    const float* b_ih   = (const float*)d_in[3];
    const float* b_hh   = (const float*)d_in[4];
    const float* W_fc   = (const float*)d_in[5];
    const float* b_fc   = (const float*)d_in[6];
    const float* h0     = (const float*)d_in[7];
    const float* c0     = (const float*)d_in[8];
    float* out = (float*)d_out;

    // ws: Wp fp16 (8 MB) | h buffers 2 x 512 KB | cnt (1 KB)
    unsigned short* Wp = (unsigned short*)d_ws;
    unsigned long long* hbase = (unsigned long long*)(Wp + (size_t)4194304);
    unsigned int* cnt = (unsigned int*)(hbase + 2 * HP_U64);

    pack_w<<<2048, 256, 0, stream>>>(W_hh, Wp);
    prep_state<<<256, 256, 0, stream>>>(h0, hbase, cnt);

    // 512 WGs x 256 threads, 80 KiB LDS -> 2 WGs/CU (independent m-groups),
    // all 512 co-resident on 256 CUs.
    lstm_persist<<<512, 256, 0, stream>>>(y_hist, W_ih, b_ih, b_hh, c0, W_fc, b_fc,
                                          Wp, hbase, cnt, out);
}